// Round 1
// baseline (238.694 us; speedup 1.0000x reference)
//
#include <hip/hip_runtime.h>
#include <hip/hip_bf16.h>
#include <cstdint>
#include <cstddef>

// Problem constants (B=2, N=2048, D=1024, H=16, DH=64, window +-64)
#define BB 2
#define NN 2048
#define DD 1024
#define HH 16
#define DHH 64
#define SCALE 0.125f

typedef _Float16 f16x8 __attribute__((ext_vector_type(8)));
typedef float f32x4 __attribute__((ext_vector_type(4)));

#define AS1(p) ((__attribute__((address_space(1))) void*)(p))
#define AS3(p) ((__attribute__((address_space(3))) void*)(p))

// ---------------- fp32 -> fp16 cast (x) ----------------
__global__ __launch_bounds__(256) void cvt_f32_to_f16(const float* __restrict__ in,
                                                      _Float16* __restrict__ out, int n) {
    int i = (blockIdx.x * 256 + threadIdx.x) * 8;
    if (i + 8 <= n) {
        f32x4 a = *(const f32x4*)(in + i);
        f32x4 b = *(const f32x4*)(in + i + 4);
        f16x8 o;
        o[0] = (_Float16)a[0]; o[1] = (_Float16)a[1]; o[2] = (_Float16)a[2]; o[3] = (_Float16)a[3];
        o[4] = (_Float16)b[0]; o[5] = (_Float16)b[1]; o[6] = (_Float16)b[2]; o[7] = (_Float16)b[3];
        *(f16x8*)(out + i) = o;
    }
}

// ---------------- fused transpose + fp16 cast (weights) ----------------
// in: [R][C] f32 row-major  ->  out: [C][R] f16 row-major
__global__ __launch_bounds__(256) void transpose_cvt(const float* __restrict__ in,
                                                     _Float16* __restrict__ out, int R, int C) {
    __shared__ float tile[32][33];
    int tx = threadIdx.x & 31, ty = threadIdx.x >> 5;  // 32 x 8
    int r0 = blockIdx.y * 32, c0 = blockIdx.x * 32;
#pragma unroll
    for (int i = 0; i < 32; i += 8)
        tile[ty + i][tx] = in[(size_t)(r0 + ty + i) * C + (c0 + tx)];
    __syncthreads();
#pragma unroll
    for (int i = 0; i < 32; i += 8)
        out[(size_t)(c0 + ty + i) * R + (r0 + tx)] = (_Float16)tile[tx][ty + i];
}

// ---------------- f16 MFMA GEMM, B pre-transposed (m97 structure) ----------------
// C[M][N] = A[M][K] @ Bt[N][K]^T + bias[N]; writes f16 (Ch) or f32 (Cf)
__global__ __launch_bounds__(256) void gemm_f16_bt(const _Float16* __restrict__ A,
                                                   const _Float16* __restrict__ Bt,
                                                   const float* __restrict__ bias,
                                                   _Float16* __restrict__ Ch,
                                                   float* __restrict__ Cf,
                                                   int M, int N, int K) {
    __shared__ __align__(16) _Float16 As[128 * 32];
    __shared__ __align__(16) _Float16 Bs[128 * 32];
    int tid = threadIdx.x;
    int wave = tid >> 6, lane = tid & 63;
    int bm = blockIdx.y * 128, bn = blockIdx.x * 128;
    int wm = (wave >> 1) * 64, wn = (wave & 1) * 64;
    int lhi = lane >> 4, llo = lane & 15;

    f32x4 acc[4][4] = {};

    // staging: 8 chunks of 1KB (16 rows x 32 halves); wave w stages chunks {2w,2w+1}
    int c0 = wave * 2, c1 = wave * 2 + 1;
    int rsub = lane >> 2;            // 0..15 row-within-chunk
    int colA = (lane & 3) * 8;       // k offset (halves)
    int rowA0 = c0 * 16 + rsub, rowA1 = c1 * 16 + rsub;
    const _Float16* gA0 = A + (size_t)(bm + rowA0) * K + colA;
    const _Float16* gA1 = A + (size_t)(bm + rowA1) * K + colA;
    const _Float16* gB0 = Bt + (size_t)(bn + rowA0) * K + colA;
    const _Float16* gB1 = Bt + (size_t)(bn + rowA1) * K + colA;
    _Float16* lA0 = As + c0 * 512;   // wave-uniform LDS bases
    _Float16* lA1 = As + c1 * 512;
    _Float16* lB0 = Bs + c0 * 512;
    _Float16* lB1 = Bs + c1 * 512;

    for (int k0 = 0; k0 < K; k0 += 32) {
        __syncthreads();
        __builtin_amdgcn_global_load_lds(AS1(gA0 + k0), AS3(lA0), 16, 0, 0);
        __builtin_amdgcn_global_load_lds(AS1(gA1 + k0), AS3(lA1), 16, 0, 0);
        __builtin_amdgcn_global_load_lds(AS1(gB0 + k0), AS3(lB0), 16, 0, 0);
        __builtin_amdgcn_global_load_lds(AS1(gB1 + k0), AS3(lB1), 16, 0, 0);
        __syncthreads();

        f16x8 af[4], bf[4];
#pragma unroll
        for (int mt = 0; mt < 4; ++mt)
            af[mt] = *(const f16x8*)(As + (wm + mt * 16 + llo) * 32 + lhi * 8);
#pragma unroll
        for (int nt = 0; nt < 4; ++nt)
            bf[nt] = *(const f16x8*)(Bs + (wn + nt * 16 + llo) * 32 + lhi * 8);
#pragma unroll
        for (int mt = 0; mt < 4; ++mt)
#pragma unroll
            for (int nt = 0; nt < 4; ++nt)
                acc[mt][nt] = __builtin_amdgcn_mfma_f32_16x16x32_f16(af[mt], bf[nt], acc[mt][nt], 0, 0, 0);
    }

    // epilogue: C/D layout col=lane&15, row=(lane>>4)*4+reg (m89/m91-verified)
#pragma unroll
    for (int nt = 0; nt < 4; ++nt) {
        int col = bn + wn + nt * 16 + llo;
        float bv = bias[col];
#pragma unroll
        for (int mt = 0; mt < 4; ++mt) {
#pragma unroll
            for (int r = 0; r < 4; ++r) {
                int row = bm + wm + mt * 16 + lhi * 4 + r;
                float v = acc[mt][nt][r] + bv;
                if (Ch) Ch[(size_t)row * N + col] = (_Float16)v;
                else    Cf[(size_t)row * N + col] = v;
            }
        }
    }
}

// ---------------- windowed attention (vector fp32, fp16 K/V in LDS) ----------------
// qkv: [B*N][3*D] f16 (q | k | v); outh: [B*N][D] f16
// block = (qtile of 64, head, batch); 256 threads = 64 queries x 4 key-groups
// key slots s in [0,192) cover j = i0-64+s; group g takes s = jj*4+g (interleaved)
#define KSTR 72  // LDS row stride in halves: 144B = 36 banks -> groups land 4 banks apart
__global__ __launch_bounds__(256) void local_attn(const _Float16* __restrict__ qkv,
                                                  _Float16* __restrict__ outh) {
    __shared__ __align__(16) _Float16 Ks[192 * KSTR];
    __shared__ __align__(16) _Float16 Vs[192 * KSTR];
    int tid = threadIdx.x;
    int i0 = blockIdx.x * 64;
    int h = blockIdx.y, b = blockIdx.z;

    // stage K,V (zero-fill out-of-range keys)
    for (int u = tid; u < 1536; u += 256) {
        int s = u >> 3, d8 = (u & 7) * 8;
        int j = i0 - 64 + s;
        f16x8 kv = {0, 0, 0, 0, 0, 0, 0, 0};
        f16x8 vv = {0, 0, 0, 0, 0, 0, 0, 0};
        if (j >= 0 && j < NN) {
            const _Float16* base = qkv + (size_t)(b * NN + j) * (3 * DD) + h * DHH + d8;
            kv = *(const f16x8*)(base + DD);
            vv = *(const f16x8*)(base + 2 * DD);
        }
        *(f16x8*)(Ks + s * KSTR + d8) = kv;
        *(f16x8*)(Vs + s * KSTR + d8) = vv;
    }

    int qL = tid >> 2, g = tid & 3;  // lanes 4q..4q+3 share a query (same wave)
    int qi = i0 + qL;
    float qreg[64];
    const _Float16* qp = qkv + (size_t)(b * NN + qi) * (3 * DD) + h * DHH;
#pragma unroll
    for (int d8 = 0; d8 < 64; d8 += 8) {
        f16x8 qv = *(const f16x8*)(qp + d8);
#pragma unroll
        for (int t = 0; t < 8; ++t) qreg[d8 + t] = (float)qv[t];
    }
    __syncthreads();

    // scores (48 keys per thread, in registers)
    float S[48];
    float m = -1e30f;
#pragma unroll
    for (int jj = 0; jj < 48; ++jj) {
        int s = jj * 4 + g;
        int j = i0 - 64 + s;
        const _Float16* kp = Ks + s * KSTR;
        float acc = 0.f;
#pragma unroll
        for (int d8 = 0; d8 < 64; d8 += 8) {
            f16x8 kv = *(const f16x8*)(kp + d8);
#pragma unroll
            for (int t = 0; t < 8; ++t) acc += qreg[d8 + t] * (float)kv[t];
        }
        int dd = j - qi;
        bool valid = (j >= 0) && (j < NN) && (dd <= 64) && (dd >= -64);
        S[jj] = valid ? acc * SCALE : -1e30f;
        m = fmaxf(m, S[jj]);
    }
    m = fmaxf(m, __shfl_xor(m, 1, 64));
    m = fmaxf(m, __shfl_xor(m, 2, 64));
    float l = 0.f;
#pragma unroll
    for (int jj = 0; jj < 48; ++jj) {
        S[jj] = __expf(S[jj] - m);
        l += S[jj];
    }
    l += __shfl_xor(l, 1, 64);
    l += __shfl_xor(l, 2, 64);
    float invl = 1.f / l;

    // P @ V, 8-wide dh chunks; partials reduced across the 4 lanes of a query
#pragma unroll
    for (int d8 = 0; d8 < 64; d8 += 8) {
        float o[8] = {0, 0, 0, 0, 0, 0, 0, 0};
#pragma unroll
        for (int jj = 0; jj < 48; ++jj) {
            int s = jj * 4 + g;
            f16x8 vv = *(const f16x8*)(Vs + s * KSTR + d8);
#pragma unroll
            for (int t = 0; t < 8; ++t) o[t] += S[jj] * (float)vv[t];
        }
#pragma unroll
        for (int t = 0; t < 8; ++t) {
            o[t] += __shfl_xor(o[t], 1, 64);
            o[t] += __shfl_xor(o[t], 2, 64);
        }
        if (g == 0) {
            f16x8 oh;
#pragma unroll
            for (int t = 0; t < 8; ++t) oh[t] = (_Float16)(o[t] * invl);
            *(f16x8*)(outh + (size_t)(b * NN + qi) * DD + h * DHH + d8) = oh;
        }
    }
}

// ---------------- launch ----------------
extern "C" void kernel_launch(void* const* d_in, const int* in_sizes, int n_in,
                              void* d_out, int out_size, void* d_ws, size_t ws_size,
                              hipStream_t stream) {
    const float* x    = (const float*)d_in[0];
    const float* Wqkv = (const float*)d_in[1];
    const float* bqkv = (const float*)d_in[2];
    const float* Wout = (const float*)d_in[3];
    const float* bout = (const float*)d_in[4];
    float* out = (float*)d_out;

    // workspace layout (48 MB total)
    char* ws = (char*)d_ws;
    _Float16* x_h    = (_Float16*)(ws);                              //  8 MB [4096][1024]
    _Float16* Wqkv_t = (_Float16*)(ws + (size_t)8  * 1024 * 1024);   //  6 MB [3072][1024]
    _Float16* Wout_t = (_Float16*)(ws + (size_t)14 * 1024 * 1024);   //  2 MB [1024][1024]
    _Float16* qkv_h  = (_Float16*)(ws + (size_t)16 * 1024 * 1024);   // 24 MB [4096][3072]
    _Float16* attn_h = (_Float16*)(ws + (size_t)40 * 1024 * 1024);   //  8 MB [4096][1024]

    int M = BB * NN;  // 4096

    cvt_f32_to_f16<<<(M * DD) / (256 * 8), 256, 0, stream>>>(x, x_h, M * DD);
    transpose_cvt<<<dim3((3 * DD) / 32, DD / 32), 256, 0, stream>>>(Wqkv, Wqkv_t, DD, 3 * DD);
    transpose_cvt<<<dim3(DD / 32, DD / 32), 256, 0, stream>>>(Wout, Wout_t, DD, DD);

    gemm_f16_bt<<<dim3((3 * DD) / 128, M / 128), 256, 0, stream>>>(
        x_h, Wqkv_t, bqkv, qkv_h, nullptr, M, 3 * DD, DD);

    local_attn<<<dim3(NN / 64, HH, BB), 256, 0, stream>>>(qkv_h, attn_h);

    gemm_f16_bt<<<dim3(DD / 128, M / 128), 256, 0, stream>>>(
        attn_h, Wout_t, bout, nullptr, out, M, DD, DD);
}

// Round 2
// 177.656 us; speedup vs baseline: 1.3436x; 1.3436x over previous
//
#include <hip/hip_runtime.h>
#include <hip/hip_bf16.h>
#include <cstdint>
#include <cstddef>

// Problem constants (B=2, N=2048, D=1024, H=16, DH=64, window +-64)
#define BB 2
#define NN 2048
#define DD 1024
#define HH 16
#define DHH 64
#define SCALE 0.125f

typedef _Float16 f16x8 __attribute__((ext_vector_type(8)));
typedef _Float16 f16x4 __attribute__((ext_vector_type(4)));
typedef float f32x4 __attribute__((ext_vector_type(4)));

#define AS1(p) ((__attribute__((address_space(1))) void*)(p))
#define AS3(p) ((__attribute__((address_space(3))) void*)(p))

// ---------------- fp32 -> fp16 cast (x) ----------------
__global__ __launch_bounds__(256) void cvt_f32_to_f16(const float* __restrict__ in,
                                                      _Float16* __restrict__ out, int n) {
    int i = (blockIdx.x * 256 + threadIdx.x) * 8;
    if (i + 8 <= n) {
        f32x4 a = *(const f32x4*)(in + i);
        f32x4 b = *(const f32x4*)(in + i + 4);
        f16x8 o;
        o[0] = (_Float16)a[0]; o[1] = (_Float16)a[1]; o[2] = (_Float16)a[2]; o[3] = (_Float16)a[3];
        o[4] = (_Float16)b[0]; o[5] = (_Float16)b[1]; o[6] = (_Float16)b[2]; o[7] = (_Float16)b[3];
        *(f16x8*)(out + i) = o;
    }
}

// ---------------- fused transpose + fp16 cast (weights) ----------------
__global__ __launch_bounds__(256) void transpose_cvt(const float* __restrict__ in,
                                                     _Float16* __restrict__ out, int R, int C) {
    __shared__ float tile[32][33];
    int tx = threadIdx.x & 31, ty = threadIdx.x >> 5;  // 32 x 8
    int r0 = blockIdx.y * 32, c0 = blockIdx.x * 32;
#pragma unroll
    for (int i = 0; i < 32; i += 8)
        tile[ty + i][tx] = in[(size_t)(r0 + ty + i) * C + (c0 + tx)];
    __syncthreads();
#pragma unroll
    for (int i = 0; i < 32; i += 8)
        out[(size_t)(c0 + ty + i) * R + (r0 + tx)] = (_Float16)tile[tx][ty + i];
}

// ---------------- f16 MFMA GEMM, B pre-transposed (m97 structure) ----------------
__global__ __launch_bounds__(256) void gemm_f16_bt(const _Float16* __restrict__ A,
                                                   const _Float16* __restrict__ Bt,
                                                   const float* __restrict__ bias,
                                                   _Float16* __restrict__ Ch,
                                                   float* __restrict__ Cf,
                                                   int M, int N, int K) {
    __shared__ __align__(16) _Float16 As[128 * 32];
    __shared__ __align__(16) _Float16 Bs[128 * 32];
    int tid = threadIdx.x;
    int wave = tid >> 6, lane = tid & 63;
    int bm = blockIdx.y * 128, bn = blockIdx.x * 128;
    int wm = (wave >> 1) * 64, wn = (wave & 1) * 64;
    int lhi = lane >> 4, llo = lane & 15;

    f32x4 acc[4][4] = {};

    int c0 = wave * 2, c1 = wave * 2 + 1;
    int rsub = lane >> 2;
    int colA = (lane & 3) * 8;
    int rowA0 = c0 * 16 + rsub, rowA1 = c1 * 16 + rsub;
    const _Float16* gA0 = A + (size_t)(bm + rowA0) * K + colA;
    const _Float16* gA1 = A + (size_t)(bm + rowA1) * K + colA;
    const _Float16* gB0 = Bt + (size_t)(bn + rowA0) * K + colA;
    const _Float16* gB1 = Bt + (size_t)(bn + rowA1) * K + colA;
    _Float16* lA0 = As + c0 * 512;
    _Float16* lA1 = As + c1 * 512;
    _Float16* lB0 = Bs + c0 * 512;
    _Float16* lB1 = Bs + c1 * 512;

    for (int k0 = 0; k0 < K; k0 += 32) {
        __syncthreads();
        __builtin_amdgcn_global_load_lds(AS1(gA0 + k0), AS3(lA0), 16, 0, 0);
        __builtin_amdgcn_global_load_lds(AS1(gA1 + k0), AS3(lA1), 16, 0, 0);
        __builtin_amdgcn_global_load_lds(AS1(gB0 + k0), AS3(lB0), 16, 0, 0);
        __builtin_amdgcn_global_load_lds(AS1(gB1 + k0), AS3(lB1), 16, 0, 0);
        __syncthreads();

        f16x8 af[4], bf[4];
#pragma unroll
        for (int mt = 0; mt < 4; ++mt)
            af[mt] = *(const f16x8*)(As + (wm + mt * 16 + llo) * 32 + lhi * 8);
#pragma unroll
        for (int nt = 0; nt < 4; ++nt)
            bf[nt] = *(const f16x8*)(Bs + (wn + nt * 16 + llo) * 32 + lhi * 8);
#pragma unroll
        for (int mt = 0; mt < 4; ++mt)
#pragma unroll
            for (int nt = 0; nt < 4; ++nt)
                acc[mt][nt] = __builtin_amdgcn_mfma_f32_16x16x32_f16(af[mt], bf[nt], acc[mt][nt], 0, 0, 0);
    }

#pragma unroll
    for (int nt = 0; nt < 4; ++nt) {
        int col = bn + wn + nt * 16 + llo;
        float bv = bias[col];
#pragma unroll
        for (int mt = 0; mt < 4; ++mt) {
#pragma unroll
            for (int r = 0; r < 4; ++r) {
                int row = bm + wm + mt * 16 + lhi * 4 + r;
                float v = acc[mt][nt][r] + bv;
                if (Ch) Ch[(size_t)row * N + col] = (_Float16)v;
                else    Cf[(size_t)row * N + col] = v;
            }
        }
    }
}

// ---------------- windowed attention via MFMA ----------------
// block = (64-query tile, head, batch); 4 waves, wave w owns queries w*16..w*16+15
// Phase 1: S^T = K @ Q^T  (A=K rows from LDS, B=Q rows from LDS, both b128)
//   C-layout: col=lane&15 = query, row=(lane>>4)*4+r = key  -> softmax per-lane + xor16/32
// Phase 2: O = P @ V      (A=P rows, B=V^T rows, both b128)
#define KP 72    // Ks stride (halves): 144B, rows 4 banks apart
#define PP 200   // Ps stride: 400B (16B-aligned), rows 4 banks apart
#define VP 200   // Vt stride
__global__ __launch_bounds__(256) void local_attn(const _Float16* __restrict__ qkv,
                                                  _Float16* __restrict__ outh) {
    __shared__ __align__(16) _Float16 Ks[192 * KP];   // 27648 B
    __shared__ __align__(16) _Float16 Ps[64 * PP];    // 25600 B (Q cols 0..63 in phase 1)
    __shared__ __align__(16) _Float16 Vt[64 * VP];    // 25600 B
    int tid = threadIdx.x;
    int i0 = blockIdx.x * 64;
    int h = blockIdx.y, b = blockIdx.z;
    const size_t rs = 3 * DD;
    const _Float16* base = qkv + (size_t)(b * NN) * rs + h * DHH;

    // --- stage K rows + V transposed (staggered scalar writes: conflict-free) ---
    for (int u = tid; u < 1536; u += 256) {
        int s = u >> 3, d8c = u & 7, d8 = d8c * 8;
        int j = i0 - 64 + s;
        f16x8 kv = {0,0,0,0,0,0,0,0}, vv = {0,0,0,0,0,0,0,0};
        if (j >= 0 && j < NN) {
            const _Float16* p = base + (size_t)j * rs + d8;
            kv = *(const f16x8*)(p + DD);
            vv = *(const f16x8*)(p + 2 * DD);
        }
        *(f16x8*)(Ks + s * KP + d8) = kv;
#pragma unroll
        for (int i = 0; i < 8; ++i) {
            int t = (i + d8c) & 7;               // stagger rows across lanes
            Vt[(d8 + t) * VP + s] = vv[t];
        }
    }
    // --- stage Q into Ps cols 0..63 ---
    for (int u = tid; u < 512; u += 256) {
        int r = u >> 3, d8 = (u & 7) * 8;
        f16x8 qv = *(const f16x8*)(base + (size_t)(i0 + r) * rs + d8);
        *(f16x8*)(Ps + r * PP + d8) = qv;
    }
    __syncthreads();

    int wave = tid >> 6, lane = tid & 63;
    int llo = lane & 15, lhi = lane >> 4;
    int qrow = wave * 16 + llo;    // query this lane owns for softmax / P-write
    int qi = i0 + qrow;

    // --- S^T = K @ Q^T (per wave: 12 key-tiles x its 16 queries, K=64) ---
    f16x8 qf0 = *(const f16x8*)(Ps + qrow * PP + lhi * 8);
    f16x8 qf1 = *(const f16x8*)(Ps + qrow * PP + 32 + lhi * 8);
    float sc[12][4];
#pragma unroll
    for (int mt = 0; mt < 12; ++mt) {
        f16x8 kf0 = *(const f16x8*)(Ks + (mt * 16 + llo) * KP + lhi * 8);
        f16x8 kf1 = *(const f16x8*)(Ks + (mt * 16 + llo) * KP + 32 + lhi * 8);
        f32x4 a = {0.f, 0.f, 0.f, 0.f};
        a = __builtin_amdgcn_mfma_f32_16x16x32_f16(kf0, qf0, a, 0, 0, 0);
        a = __builtin_amdgcn_mfma_f32_16x16x32_f16(kf1, qf1, a, 0, 0, 0);
#pragma unroll
        for (int r = 0; r < 4; ++r) sc[mt][r] = a[r];
    }

    // --- masked softmax over 192 keys of query qi ---
    float m = -1e30f;
#pragma unroll
    for (int mt = 0; mt < 12; ++mt)
#pragma unroll
        for (int r = 0; r < 4; ++r) {
            int sidx = mt * 16 + lhi * 4 + r;
            int j = i0 - 64 + sidx;
            int dj = j - qi;
            bool valid = (j >= 0) && (j < NN) && (dj <= 64) && (dj >= -64);
            float v = valid ? sc[mt][r] * SCALE : -1e30f;
            sc[mt][r] = v;
            m = fmaxf(m, v);
        }
    m = fmaxf(m, __shfl_xor(m, 16, 64));
    m = fmaxf(m, __shfl_xor(m, 32, 64));
    float l = 0.f;
#pragma unroll
    for (int mt = 0; mt < 12; ++mt)
#pragma unroll
        for (int r = 0; r < 4; ++r) {
            float e = __expf(sc[mt][r] - m);   // masked: exp(-huge) -> 0
            sc[mt][r] = e;
            l += e;
        }
    l += __shfl_xor(l, 16, 64);
    l += __shfl_xor(l, 32, 64);
    float invl = 1.f / l;

    // --- write normalized P rows (overlays Q region; own-wave rows only) ---
#pragma unroll
    for (int mt = 0; mt < 12; ++mt) {
        f16x4 pv;
#pragma unroll
        for (int r = 0; r < 4; ++r) pv[r] = (_Float16)(sc[mt][r] * invl);
        *(f16x4*)(Ps + qrow * PP + mt * 16 + lhi * 4) = pv;
    }
    __asm__ volatile("s_waitcnt lgkmcnt(0)" ::: "memory");  // wave-local P write->read

    // --- O = P @ V (per wave: 16 queries x 64 dh, K=192) ---
    f32x4 oacc[4] = {};
#pragma unroll
    for (int ks = 0; ks < 6; ++ks) {
        f16x8 pf = *(const f16x8*)(Ps + (wave * 16 + llo) * PP + ks * 32 + lhi * 8);
#pragma unroll
        for (int nt = 0; nt < 4; ++nt) {
            f16x8 vf = *(const f16x8*)(Vt + (nt * 16 + llo) * VP + ks * 32 + lhi * 8);
            oacc[nt] = __builtin_amdgcn_mfma_f32_16x16x32_f16(pf, vf, oacc[nt], 0, 0, 0);
        }
    }

    // --- epilogue: C-layout col=llo=dh, row=lhi*4+r=query ---
    _Float16* orow = outh + (size_t)(b * NN) * DD + h * DHH;
#pragma unroll
    for (int nt = 0; nt < 4; ++nt)
#pragma unroll
        for (int r = 0; r < 4; ++r) {
            int q = wave * 16 + lhi * 4 + r;
            int d = nt * 16 + llo;
            orow[(size_t)(i0 + q) * DD + d] = (_Float16)oacc[nt][r];
        }
}

// ---------------- launch ----------------
extern "C" void kernel_launch(void* const* d_in, const int* in_sizes, int n_in,
                              void* d_out, int out_size, void* d_ws, size_t ws_size,
                              hipStream_t stream) {
    const float* x    = (const float*)d_in[0];
    const float* Wqkv = (const float*)d_in[1];
    const float* bqkv = (const float*)d_in[2];
    const float* Wout = (const float*)d_in[3];
    const float* bout = (const float*)d_in[4];
    float* out = (float*)d_out;

    char* ws = (char*)d_ws;
    _Float16* x_h    = (_Float16*)(ws);                              //  8 MB
    _Float16* Wqkv_t = (_Float16*)(ws + (size_t)8  * 1024 * 1024);   //  6 MB
    _Float16* Wout_t = (_Float16*)(ws + (size_t)14 * 1024 * 1024);   //  2 MB
    _Float16* qkv_h  = (_Float16*)(ws + (size_t)16 * 1024 * 1024);   // 24 MB
    _Float16* attn_h = (_Float16*)(ws + (size_t)40 * 1024 * 1024);   //  8 MB

    int M = BB * NN;  // 4096

    cvt_f32_to_f16<<<(M * DD) / (256 * 8), 256, 0, stream>>>(x, x_h, M * DD);
    transpose_cvt<<<dim3((3 * DD) / 32, DD / 32), 256, 0, stream>>>(Wqkv, Wqkv_t, DD, 3 * DD);
    transpose_cvt<<<dim3(DD / 32, DD / 32), 256, 0, stream>>>(Wout, Wout_t, DD, DD);

    gemm_f16_bt<<<dim3((3 * DD) / 128, M / 128), 256, 0, stream>>>(
        x_h, Wqkv_t, bqkv, qkv_h, nullptr, M, 3 * DD, DD);

    local_attn<<<dim3(NN / 64, HH, BB), 256, 0, stream>>>(qkv_h, attn_h);

    gemm_f16_bt<<<dim3(DD / 128, M / 128), 256, 0, stream>>>(
        attn_h, Wout_t, bout, nullptr, out, M, DD, DD);
}

// Round 3
// 165.786 us; speedup vs baseline: 1.4398x; 1.0716x over previous
//
#include <hip/hip_runtime.h>
#include <hip/hip_bf16.h>
#include <cstdint>
#include <cstddef>

// Problem constants (B=2, N=2048, D=1024, H=16, DH=64, window +-64)
#define BB 2
#define NN 2048
#define DD 1024
#define HH 16
#define DHH 64
#define SCALE 0.125f

typedef _Float16 f16x8 __attribute__((ext_vector_type(8)));
typedef _Float16 f16x4 __attribute__((ext_vector_type(4)));
typedef float f32x4 __attribute__((ext_vector_type(4)));

#define AS1(p) ((__attribute__((address_space(1))) void*)(p))
#define AS3(p) ((__attribute__((address_space(3))) void*)(p))

// ---------------- fp32 -> fp16 cast (x) ----------------
__global__ __launch_bounds__(256) void cvt_f32_to_f16(const float* __restrict__ in,
                                                      _Float16* __restrict__ out, int n) {
    int i = (blockIdx.x * 256 + threadIdx.x) * 8;
    if (i + 8 <= n) {
        f32x4 a = *(const f32x4*)(in + i);
        f32x4 b = *(const f32x4*)(in + i + 4);
        f16x8 o;
        o[0] = (_Float16)a[0]; o[1] = (_Float16)a[1]; o[2] = (_Float16)a[2]; o[3] = (_Float16)a[3];
        o[4] = (_Float16)b[0]; o[5] = (_Float16)b[1]; o[6] = (_Float16)b[2]; o[7] = (_Float16)b[3];
        *(f16x8*)(out + i) = o;
    }
}

// ---------------- fused transpose + fp16 cast (weights) ----------------
__global__ __launch_bounds__(256) void transpose_cvt(const float* __restrict__ in,
                                                     _Float16* __restrict__ out, int R, int C) {
    __shared__ float tile[32][33];
    int tx = threadIdx.x & 31, ty = threadIdx.x >> 5;  // 32 x 8
    int r0 = blockIdx.y * 32, c0 = blockIdx.x * 32;
#pragma unroll
    for (int i = 0; i < 32; i += 8)
        tile[ty + i][tx] = in[(size_t)(r0 + ty + i) * C + (c0 + tx)];
    __syncthreads();
#pragma unroll
    for (int i = 0; i < 32; i += 8)
        out[(size_t)(c0 + ty + i) * R + (r0 + tx)] = (_Float16)tile[tx][ty + i];
}

// ---------------- f16 MFMA GEMM, B pre-transposed, BK=64, XOR-swizzled LDS ----------------
// LDS layout: As[row][64 halves], where 16B chunk slot c_l of row r holds global
// chunk c_g = c_l ^ (r&7). Staging: lane L writes slot (rowbase+(L>>3), L&7) at
// base + L*16B (wave-uniform base => global_load_lds-legal), reading global chunk
// (L&7)^(L>>3) of its row (wave/pass invariant!). Fragment reads apply the same XOR.
__global__ __launch_bounds__(256) void gemm_f16_bt(const _Float16* __restrict__ A,
                                                   const _Float16* __restrict__ Bt,
                                                   const float* __restrict__ bias,
                                                   _Float16* __restrict__ Ch,
                                                   float* __restrict__ Cf,
                                                   int M, int N, int K) {
    __shared__ __align__(16) _Float16 As[128 * 64];
    __shared__ __align__(16) _Float16 Bs[128 * 64];
    int tid = threadIdx.x;
    int wave = tid >> 6, lane = tid & 63;
    int bm = blockIdx.y * 128, bn = blockIdx.x * 128;
    int wm = (wave >> 1) * 64, wn = (wave & 1) * 64;
    int lhi = lane >> 4, llo = lane & 15;

    f32x4 acc[4][4] = {};

    // staging: wave w covers rows 32w..32w+31 of each tile; pass p rows +8p..+8p+7
    int srow = wave * 32 + (lane >> 3);
    int scol = (((lane & 7) ^ (lane >> 3))) * 8;   // swizzled global chunk (halves)
    const _Float16* gA = A + (size_t)(bm + srow) * K + scol;
    const _Float16* gB = Bt + (size_t)(bn + srow) * K + scol;
    _Float16* lA = As + wave * 2048 + lane * 8;    // wave-uniform base + lane*16B
    _Float16* lB = Bs + wave * 2048 + lane * 8;

    for (int k0 = 0; k0 < K; k0 += 64) {
        __syncthreads();
#pragma unroll
        for (int p = 0; p < 4; ++p) {
            __builtin_amdgcn_global_load_lds(AS1(gA + (size_t)p * 8 * K + k0), AS3(lA + p * 512), 16, 0, 0);
            __builtin_amdgcn_global_load_lds(AS1(gB + (size_t)p * 8 * K + k0), AS3(lB + p * 512), 16, 0, 0);
        }
        __syncthreads();

#pragma unroll
        for (int ks = 0; ks < 2; ++ks) {
            f16x8 af[4], bf[4];
            int cc = ks * 4 + lhi;
            int swzA = ((cc ^ (llo & 7)) * 8);     // row&7 == llo&7 (wm,16*mt are mult of 8)
#pragma unroll
            for (int mt = 0; mt < 4; ++mt)
                af[mt] = *(const f16x8*)(As + (wm + mt * 16 + llo) * 64 + swzA);
#pragma unroll
            for (int nt = 0; nt < 4; ++nt)
                bf[nt] = *(const f16x8*)(Bs + (wn + nt * 16 + llo) * 64 + swzA);
#pragma unroll
            for (int mt = 0; mt < 4; ++mt)
#pragma unroll
                for (int nt = 0; nt < 4; ++nt)
                    acc[mt][nt] = __builtin_amdgcn_mfma_f32_16x16x32_f16(af[mt], bf[nt], acc[mt][nt], 0, 0, 0);
        }
    }

    // epilogue: C/D layout col=lane&15, row=(lane>>4)*4+reg
#pragma unroll
    for (int nt = 0; nt < 4; ++nt) {
        int col = bn + wn + nt * 16 + llo;
        float bv = bias[col];
#pragma unroll
        for (int mt = 0; mt < 4; ++mt) {
#pragma unroll
            for (int r = 0; r < 4; ++r) {
                int row = bm + wm + mt * 16 + lhi * 4 + r;
                float v = acc[mt][nt][r] + bv;
                if (Ch) Ch[(size_t)row * N + col] = (_Float16)v;
                else    Cf[(size_t)row * N + col] = v;
            }
        }
    }
}

// ---------------- windowed attention via MFMA ----------------
#define KP 72    // Ks stride (halves): 144B, rows 4 banks apart
#define PP 200   // Ps stride: 400B (16B-aligned), rows 4 banks apart
#define VP 200   // Vt stride
__global__ __launch_bounds__(256) void local_attn(const _Float16* __restrict__ qkv,
                                                  _Float16* __restrict__ outh) {
    __shared__ __align__(16) _Float16 Ks[192 * KP];
    __shared__ __align__(16) _Float16 Ps[64 * PP];
    __shared__ __align__(16) _Float16 Vt[64 * VP];
    int tid = threadIdx.x;
    int i0 = blockIdx.x * 64;
    int h = blockIdx.y, b = blockIdx.z;
    const size_t rs = 3 * DD;
    const _Float16* base = qkv + (size_t)(b * NN) * rs + h * DHH;

    for (int u = tid; u < 1536; u += 256) {
        int s = u >> 3, d8c = u & 7, d8 = d8c * 8;
        int j = i0 - 64 + s;
        f16x8 kv = {0,0,0,0,0,0,0,0}, vv = {0,0,0,0,0,0,0,0};
        if (j >= 0 && j < NN) {
            const _Float16* p = base + (size_t)j * rs + d8;
            kv = *(const f16x8*)(p + DD);
            vv = *(const f16x8*)(p + 2 * DD);
        }
        *(f16x8*)(Ks + s * KP + d8) = kv;
#pragma unroll
        for (int i = 0; i < 8; ++i) {
            int t = (i + d8c) & 7;
            Vt[(d8 + t) * VP + s] = vv[t];
        }
    }
    for (int u = tid; u < 512; u += 256) {
        int r = u >> 3, d8 = (u & 7) * 8;
        f16x8 qv = *(const f16x8*)(base + (size_t)(i0 + r) * rs + d8);
        *(f16x8*)(Ps + r * PP + d8) = qv;
    }
    __syncthreads();

    int wave = tid >> 6, lane = tid & 63;
    int llo = lane & 15, lhi = lane >> 4;
    int qrow = wave * 16 + llo;
    int qi = i0 + qrow;

    f16x8 qf0 = *(const f16x8*)(Ps + qrow * PP + lhi * 8);
    f16x8 qf1 = *(const f16x8*)(Ps + qrow * PP + 32 + lhi * 8);
    float sc[12][4];
#pragma unroll
    for (int mt = 0; mt < 12; ++mt) {
        f16x8 kf0 = *(const f16x8*)(Ks + (mt * 16 + llo) * KP + lhi * 8);
        f16x8 kf1 = *(const f16x8*)(Ks + (mt * 16 + llo) * KP + 32 + lhi * 8);
        f32x4 a = {0.f, 0.f, 0.f, 0.f};
        a = __builtin_amdgcn_mfma_f32_16x16x32_f16(kf0, qf0, a, 0, 0, 0);
        a = __builtin_amdgcn_mfma_f32_16x16x32_f16(kf1, qf1, a, 0, 0, 0);
#pragma unroll
        for (int r = 0; r < 4; ++r) sc[mt][r] = a[r];
    }

    float m = -1e30f;
#pragma unroll
    for (int mt = 0; mt < 12; ++mt)
#pragma unroll
        for (int r = 0; r < 4; ++r) {
            int sidx = mt * 16 + lhi * 4 + r;
            int j = i0 - 64 + sidx;
            int dj = j - qi;
            bool valid = (j >= 0) && (j < NN) && (dj <= 64) && (dj >= -64);
            float v = valid ? sc[mt][r] * SCALE : -1e30f;
            sc[mt][r] = v;
            m = fmaxf(m, v);
        }
    m = fmaxf(m, __shfl_xor(m, 16, 64));
    m = fmaxf(m, __shfl_xor(m, 32, 64));
    float l = 0.f;
#pragma unroll
    for (int mt = 0; mt < 12; ++mt)
#pragma unroll
        for (int r = 0; r < 4; ++r) {
            float e = __expf(sc[mt][r] - m);
            sc[mt][r] = e;
            l += e;
        }
    l += __shfl_xor(l, 16, 64);
    l += __shfl_xor(l, 32, 64);
    float invl = 1.f / l;

#pragma unroll
    for (int mt = 0; mt < 12; ++mt) {
        f16x4 pv;
#pragma unroll
        for (int r = 0; r < 4; ++r) pv[r] = (_Float16)(sc[mt][r] * invl);
        *(f16x4*)(Ps + qrow * PP + mt * 16 + lhi * 4) = pv;
    }
    __asm__ volatile("s_waitcnt lgkmcnt(0)" ::: "memory");

    f32x4 oacc[4] = {};
#pragma unroll
    for (int ks = 0; ks < 6; ++ks) {
        f16x8 pf = *(const f16x8*)(Ps + (wave * 16 + llo) * PP + ks * 32 + lhi * 8);
#pragma unroll
        for (int nt = 0; nt < 4; ++nt) {
            f16x8 vf = *(const f16x8*)(Vt + (nt * 16 + llo) * VP + ks * 32 + lhi * 8);
            oacc[nt] = __builtin_amdgcn_mfma_f32_16x16x32_f16(pf, vf, oacc[nt], 0, 0, 0);
        }
    }

    _Float16* orow = outh + (size_t)(b * NN) * DD + h * DHH;
#pragma unroll
    for (int nt = 0; nt < 4; ++nt)
#pragma unroll
        for (int r = 0; r < 4; ++r) {
            int q = wave * 16 + lhi * 4 + r;
            int d = nt * 16 + llo;
            orow[(size_t)(i0 + q) * DD + d] = (_Float16)oacc[nt][r];
        }
}

// ---------------- launch ----------------
extern "C" void kernel_launch(void* const* d_in, const int* in_sizes, int n_in,
                              void* d_out, int out_size, void* d_ws, size_t ws_size,
                              hipStream_t stream) {
    const float* x    = (const float*)d_in[0];
    const float* Wqkv = (const float*)d_in[1];
    const float* bqkv = (const float*)d_in[2];
    const float* Wout = (const float*)d_in[3];
    const float* bout = (const float*)d_in[4];
    float* out = (float*)d_out;

    char* ws = (char*)d_ws;
    _Float16* x_h    = (_Float16*)(ws);                              //  8 MB
    _Float16* Wqkv_t = (_Float16*)(ws + (size_t)8  * 1024 * 1024);   //  6 MB
    _Float16* Wout_t = (_Float16*)(ws + (size_t)14 * 1024 * 1024);   //  2 MB
    _Float16* qkv_h  = (_Float16*)(ws + (size_t)16 * 1024 * 1024);   // 24 MB
    _Float16* attn_h = (_Float16*)(ws + (size_t)40 * 1024 * 1024);   //  8 MB

    int M = BB * NN;  // 4096

    cvt_f32_to_f16<<<(M * DD) / (256 * 8), 256, 0, stream>>>(x, x_h, M * DD);
    transpose_cvt<<<dim3((3 * DD) / 32, DD / 32), 256, 0, stream>>>(Wqkv, Wqkv_t, DD, 3 * DD);
    transpose_cvt<<<dim3(DD / 32, DD / 32), 256, 0, stream>>>(Wout, Wout_t, DD, DD);

    gemm_f16_bt<<<dim3((3 * DD) / 128, M / 128), 256, 0, stream>>>(
        x_h, Wqkv_t, bqkv, qkv_h, nullptr, M, 3 * DD, DD);

    local_attn<<<dim3(NN / 64, HH, BB), 256, 0, stream>>>(qkv_h, attn_h);

    gemm_f16_bt<<<dim3(DD / 128, M / 128), 256, 0, stream>>>(
        attn_h, Wout_t, bout, nullptr, out, M, DD, DD);
}

// Round 4
// 159.465 us; speedup vs baseline: 1.4968x; 1.0396x over previous
//
#include <hip/hip_runtime.h>
#include <hip/hip_bf16.h>
#include <cstdint>
#include <cstddef>

// Problem constants (B=2, N=2048, D=1024, H=16, DH=64, window +-64)
#define BB 2
#define NN 2048
#define DD 1024
#define HH 16
#define DHH 64
#define SCALE 0.125f

typedef _Float16 f16x8 __attribute__((ext_vector_type(8)));
typedef _Float16 f16x4 __attribute__((ext_vector_type(4)));
typedef float f32x4 __attribute__((ext_vector_type(4)));

#define AS1(p) ((__attribute__((address_space(1))) void*)(p))
#define AS3(p) ((__attribute__((address_space(3))) void*)(p))

// ---------------- fused prep: x cast + both weight transposes, one launch ----------------
// blocks [0,2048): cast x (2048 f32 each); [2048,5120): Wqkv 32x32 transpose tiles;
// [5120,6144): Wout 32x32 transpose tiles.
__global__ __launch_bounds__(256) void prep(const float* __restrict__ x, _Float16* __restrict__ x_h,
                                            const float* __restrict__ Wqkv, _Float16* __restrict__ Wqkv_t,
                                            const float* __restrict__ Wout, _Float16* __restrict__ Wout_t) {
    __shared__ float tile[32][33];
    int bx = blockIdx.x, tid = threadIdx.x;
    if (bx < 2048) {
        int i = bx * 2048 + tid * 8;
        f32x4 a = *(const f32x4*)(x + i);
        f32x4 b = *(const f32x4*)(x + i + 4);
        f16x8 o;
        o[0] = (_Float16)a[0]; o[1] = (_Float16)a[1]; o[2] = (_Float16)a[2]; o[3] = (_Float16)a[3];
        o[4] = (_Float16)b[0]; o[5] = (_Float16)b[1]; o[6] = (_Float16)b[2]; o[7] = (_Float16)b[3];
        *(f16x8*)(x_h + i) = o;
        return;
    }
    const float* in; _Float16* out; int C, tc, tr;
    if (bx < 5120) { int t = bx - 2048; C = 3 * DD; in = Wqkv; out = Wqkv_t; tc = t % 96; tr = t / 96; }
    else           { int t = bx - 5120; C = DD;     in = Wout; out = Wout_t; tc = t % 32; tr = t / 32; }
    int R = DD;
    int txx = tid & 31, ty = tid >> 5;
    int r0 = tr * 32, c0 = tc * 32;
#pragma unroll
    for (int i = 0; i < 32; i += 8)
        tile[ty + i][txx] = in[(size_t)(r0 + ty + i) * C + (c0 + txx)];
    __syncthreads();
#pragma unroll
    for (int i = 0; i < 32; i += 8)
        out[(size_t)(c0 + ty + i) * R + (r0 + txx)] = (_Float16)tile[txx][ty + i];
}

// ---------------- f16 MFMA GEMM, B pre-transposed, BK=64, XOR-swizzled LDS ----------------
// BM=128: 2x2 waves of 64x64 (acc 4x4). BM=64: 2x2 waves of 32x64 (acc 2x4), for
// small-N GEMMs that need >1 block/CU. LDS slot c_l of row r holds global chunk
// c_l^(r&7); staging lane L reads global chunk (L&7)^(L>>3) (wave/pass-invariant)
// so global_load_lds's uniform-base+lane*16 constraint holds.
template <int BM>
__global__ __launch_bounds__(256) void gemm_f16_bt(const _Float16* __restrict__ A,
                                                   const _Float16* __restrict__ Bt,
                                                   const float* __restrict__ bias,
                                                   _Float16* __restrict__ Ch,
                                                   float* __restrict__ Cf,
                                                   int M, int N, int K) {
    constexpr int MT = BM / 32;   // m-tiles per wave
    constexpr int AP = BM / 32;   // A staging passes per wave
    __shared__ __align__(16) _Float16 As[BM * 64];
    __shared__ __align__(16) _Float16 Bs[128 * 64];
    int tid = threadIdx.x;
    int wave = tid >> 6, lane = tid & 63;
    int bm = blockIdx.y * BM, bn = blockIdx.x * 128;
    int wm = (wave >> 1) * (BM / 2), wn = (wave & 1) * 64;
    int lhi = lane >> 4, llo = lane & 15;

    f32x4 acc[MT][4] = {};

    int srowA = wave * (BM / 4) + (lane >> 3);
    int srowB = wave * 32 + (lane >> 3);
    int scol = ((lane & 7) ^ (lane >> 3)) * 8;
    const _Float16* gA = A + (size_t)(bm + srowA) * K + scol;
    const _Float16* gB = Bt + (size_t)(bn + srowB) * K + scol;
    _Float16* lA = As + wave * (AP * 512) + lane * 8;
    _Float16* lB = Bs + wave * 2048 + lane * 8;

    for (int k0 = 0; k0 < K; k0 += 64) {
        __syncthreads();
#pragma unroll
        for (int p = 0; p < AP; ++p)
            __builtin_amdgcn_global_load_lds(AS1(gA + (size_t)p * 8 * K + k0), AS3(lA + p * 512), 16, 0, 0);
#pragma unroll
        for (int p = 0; p < 4; ++p)
            __builtin_amdgcn_global_load_lds(AS1(gB + (size_t)p * 8 * K + k0), AS3(lB + p * 512), 16, 0, 0);
        __syncthreads();

#pragma unroll
        for (int ks = 0; ks < 2; ++ks) {
            f16x8 af[MT], bf[4];
            int swz = (((ks * 4 + lhi) ^ (llo & 7)) * 8);
#pragma unroll
            for (int mt = 0; mt < MT; ++mt)
                af[mt] = *(const f16x8*)(As + (wm + mt * 16 + llo) * 64 + swz);
#pragma unroll
            for (int nt = 0; nt < 4; ++nt)
                bf[nt] = *(const f16x8*)(Bs + (wn + nt * 16 + llo) * 64 + swz);
#pragma unroll
            for (int mt = 0; mt < MT; ++mt)
#pragma unroll
                for (int nt = 0; nt < 4; ++nt)
                    acc[mt][nt] = __builtin_amdgcn_mfma_f32_16x16x32_f16(af[mt], bf[nt], acc[mt][nt], 0, 0, 0);
        }
    }

    // epilogue: C/D layout col=lane&15, row=(lane>>4)*4+reg
#pragma unroll
    for (int nt = 0; nt < 4; ++nt) {
        int col = bn + wn + nt * 16 + llo;
        float bv = bias[col];
#pragma unroll
        for (int mt = 0; mt < MT; ++mt) {
#pragma unroll
            for (int r = 0; r < 4; ++r) {
                int row = bm + wm + mt * 16 + lhi * 4 + r;
                float v = acc[mt][nt][r] + bv;
                if (Ch) Ch[(size_t)row * N + col] = (_Float16)v;
                else    Cf[(size_t)row * N + col] = v;
            }
        }
    }
}

// ---------------- windowed attention via MFMA ----------------
// K staged async via global_load_lds with XOR swizzle (KP=64, conflict-free);
// Q fragments loaded global->VGPR directly; V transposed via staggered scalar
// writes (zero-filled out of range). Out-of-range K reads hit mapped d_ws
// garbage; the mask SELECTS -1e30 so garbage never propagates, and P=0 there.
#define KP 64
#define PP 200   // P stride: 400B (16B-aligned), rows 4 banks apart
#define VP 200
__global__ __launch_bounds__(256) void local_attn(const _Float16* __restrict__ qkv,
                                                  _Float16* __restrict__ outh) {
    __shared__ __align__(16) _Float16 Ks[192 * KP];   // 24576 B (swizzled)
    __shared__ __align__(16) _Float16 Ps[64 * PP];    // 25600 B
    __shared__ __align__(16) _Float16 Vt[64 * VP];    // 25600 B
    int tid = threadIdx.x;
    int i0 = blockIdx.x * 64;
    int h = blockIdx.y, b = blockIdx.z;
    const ptrdiff_t rs = 3 * DD;
    const _Float16* base = qkv + (ptrdiff_t)(b * NN) * rs + h * DHH;

    int wave = tid >> 6, lane = tid & 63;
    int llo = lane & 15, lhi = lane >> 4;

    // --- async K staging: 24 passes of 8 rows; wave w -> passes 6w..6w+5 ---
    {
        int srow = lane >> 3;
        int chunk = ((lane & 7) ^ (lane >> 3)) * 8;   // swizzled global chunk (halves)
#pragma unroll
        for (int q = 0; q < 6; ++q) {
            int p = wave * 6 + q;
            int j = i0 - 64 + p * 8 + srow;           // may be out of [0,NN): mapped garbage, masked later
            const _Float16* g = base + (ptrdiff_t)j * rs + DD + chunk;
            __builtin_amdgcn_global_load_lds(AS1(g), AS3(Ks + p * 512 + lane * 8), 16, 0, 0);
        }
    }

    // --- V transposed staging (staggered scalar writes; zero-fill OOR) ---
    for (int u = tid; u < 1536; u += 256) {
        int s = u >> 3, d8c = u & 7, d8 = d8c * 8;
        int j = i0 - 64 + s;
        f16x8 vv = {0,0,0,0,0,0,0,0};
        if (j >= 0 && j < NN)
            vv = *(const f16x8*)(base + (ptrdiff_t)j * rs + 2 * DD + d8);
#pragma unroll
        for (int i = 0; i < 8; ++i) {
            int t = (i + d8c) & 7;
            Vt[(d8 + t) * VP + s] = vv[t];
        }
    }

    // --- Q fragments straight from global ---
    int qrow = wave * 16 + llo;
    int qi = i0 + qrow;
    const _Float16* qp = base + (ptrdiff_t)qi * rs;
    f16x8 qf0 = *(const f16x8*)(qp + lhi * 8);
    f16x8 qf1 = *(const f16x8*)(qp + 32 + lhi * 8);
    __syncthreads();

    // --- S^T = K @ Q^T (swizzled Ks reads; row&7 == llo&7) ---
    float sc[12][4];
#pragma unroll
    for (int mt = 0; mt < 12; ++mt) {
        const _Float16* kr = Ks + (mt * 16 + llo) * 64;
        f16x8 kf0 = *(const f16x8*)(kr + ((lhi ^ (llo & 7)) * 8));
        f16x8 kf1 = *(const f16x8*)(kr + (((lhi + 4) ^ (llo & 7)) * 8));
        f32x4 a = {0.f, 0.f, 0.f, 0.f};
        a = __builtin_amdgcn_mfma_f32_16x16x32_f16(kf0, qf0, a, 0, 0, 0);
        a = __builtin_amdgcn_mfma_f32_16x16x32_f16(kf1, qf1, a, 0, 0, 0);
#pragma unroll
        for (int r = 0; r < 4; ++r) sc[mt][r] = a[r];
    }

    // --- masked softmax over 192 slots of query qi ---
    float m = -1e30f;
#pragma unroll
    for (int mt = 0; mt < 12; ++mt)
#pragma unroll
        for (int r = 0; r < 4; ++r) {
            int sidx = mt * 16 + lhi * 4 + r;
            int j = i0 - 64 + sidx;
            int dj = j - qi;
            bool valid = (j >= 0) && (j < NN) && (dj <= 64) && (dj >= -64);
            float v = valid ? sc[mt][r] * SCALE : -1e30f;   // select: garbage/NaN never propagates
            sc[mt][r] = v;
            m = fmaxf(m, v);
        }
    m = fmaxf(m, __shfl_xor(m, 16, 64));
    m = fmaxf(m, __shfl_xor(m, 32, 64));
    float l = 0.f;
#pragma unroll
    for (int mt = 0; mt < 12; ++mt)
#pragma unroll
        for (int r = 0; r < 4; ++r) {
            float e = __expf(sc[mt][r] - m);
            sc[mt][r] = e;
            l += e;
        }
    l += __shfl_xor(l, 16, 64);
    l += __shfl_xor(l, 32, 64);
    float invl = 1.f / l;

    // --- write normalized P rows (lane owns row qrow, slots mt*16+lhi*4..+3) ---
#pragma unroll
    for (int mt = 0; mt < 12; ++mt) {
        f16x4 pv;
#pragma unroll
        for (int r = 0; r < 4; ++r) pv[r] = (_Float16)(sc[mt][r] * invl);
        *(f16x4*)(Ps + qrow * PP + mt * 16 + lhi * 4) = pv;
    }
    __asm__ volatile("s_waitcnt lgkmcnt(0)" ::: "memory");  // wave-local P write->read

    // --- O = P @ V ---
    f32x4 oacc[4] = {};
#pragma unroll
    for (int ks = 0; ks < 6; ++ks) {
        f16x8 pf = *(const f16x8*)(Ps + (wave * 16 + llo) * PP + ks * 32 + lhi * 8);
#pragma unroll
        for (int nt = 0; nt < 4; ++nt) {
            f16x8 vf = *(const f16x8*)(Vt + (nt * 16 + llo) * VP + ks * 32 + lhi * 8);
            oacc[nt] = __builtin_amdgcn_mfma_f32_16x16x32_f16(pf, vf, oacc[nt], 0, 0, 0);
        }
    }

    // --- epilogue: col=llo=dh, row=lhi*4+r=query ---
    _Float16* orow = outh + (size_t)(b * NN) * DD + h * DHH;
#pragma unroll
    for (int nt = 0; nt < 4; ++nt)
#pragma unroll
        for (int r = 0; r < 4; ++r) {
            int q = wave * 16 + lhi * 4 + r;
            int d = nt * 16 + llo;
            orow[(size_t)(i0 + q) * DD + d] = (_Float16)oacc[nt][r];
        }
}

// ---------------- launch ----------------
extern "C" void kernel_launch(void* const* d_in, const int* in_sizes, int n_in,
                              void* d_out, int out_size, void* d_ws, size_t ws_size,
                              hipStream_t stream) {
    const float* x    = (const float*)d_in[0];
    const float* Wqkv = (const float*)d_in[1];
    const float* bqkv = (const float*)d_in[2];
    const float* Wout = (const float*)d_in[3];
    const float* bout = (const float*)d_in[4];
    float* out = (float*)d_out;

    char* ws = (char*)d_ws;
    _Float16* x_h    = (_Float16*)(ws);                              //  8 MB
    _Float16* Wqkv_t = (_Float16*)(ws + (size_t)8  * 1024 * 1024);   //  6 MB
    _Float16* Wout_t = (_Float16*)(ws + (size_t)14 * 1024 * 1024);   //  2 MB
    _Float16* qkv_h  = (_Float16*)(ws + (size_t)16 * 1024 * 1024);   // 24 MB
    _Float16* attn_h = (_Float16*)(ws + (size_t)40 * 1024 * 1024);   //  8 MB

    int M = BB * NN;  // 4096

    prep<<<6144, 256, 0, stream>>>(x, x_h, Wqkv, Wqkv_t, Wout, Wout_t);

    gemm_f16_bt<128><<<dim3((3 * DD) / 128, M / 128), 256, 0, stream>>>(
        x_h, Wqkv_t, bqkv, qkv_h, nullptr, M, 3 * DD, DD);

    local_attn<<<dim3(NN / 64, HH, BB), 256, 0, stream>>>(qkv_h, attn_h);

    gemm_f16_bt<64><<<dim3(DD / 128, M / 64), 256, 0, stream>>>(
        attn_h, Wout_t, bout, nullptr, out, M, DD, DD);
}